// Round 4
// baseline (435.915 us; speedup 1.0000x reference)
//
#include <hip/hip_runtime.h>

#define NB 1024
#define NV 6890
#define NJ 24
#define NBETA 10
#define NPOSE 207
#define NK 19
#define NKJ 456       // 19*24
#define NCOL 1368     // 3*456
#define KR 218        // coef rows: 207 pose + 10 beta + 1 const
#define AR 219        // GEMM A rows: KR + s-row
#define ATP 224       // padded A row length
#define VSTR 20670    // 3*NV
#define KSPLIT 16
#define CHP 431       // ceil(NV/KSPLIT)

// workspace layout (floats)
#define OFF_C    0ull
#define SZ_C     ((size_t)NV*NKJ)            // 3,141,840
#define OFF_AT   (OFF_C + SZ_C)
#define SZ_AT    (3ull*NV*ATP)               // 4,630,080
#define OFF_OUT  (OFF_AT + SZ_AT)
#define SZ_OUT   ((size_t)AR*NCOL)           // 299,592
#define OFF_COEF (OFF_OUT + SZ_OUT)
#define SZ_COEF  ((size_t)KR*NB)             // 223,232
#define OFF_AW   (OFF_COEF + SZ_COEF)
#define SZ_AW    ((size_t)NB*288)            // 294,912
#define OFF_JS   (OFF_AW + SZ_AW)
#define SZ_JS    (11ull*24*3)                // 792
#define OFF_M    (OFF_JS + SZ_JS)
#define SZ_M     ((size_t)NB*NCOL)           // 1,400,832
// total ~40 MB

// c[v][kj] = joint_regressor[v,k] * weights[v,j]  (float4: 4 consecutive j, same k)
__global__ void k_cw(const float* __restrict__ jr, const float* __restrict__ w,
                     float* __restrict__ cw) {
    int idx = blockIdx.x * 256 + threadIdx.x;
    if (idx >= NV * (NKJ / 4)) return;
    int v = idx / (NKJ / 4), q = idx - v * (NKJ / 4);
    int kj0 = q * 4;
    int k = kj0 / NJ, j0 = kj0 - k * NJ;      // j0 in {0,4,...,20}: all 4 share k
    float jv = jr[v * NK + k];
    float4 wv = *(const float4*)&w[v * NJ + j0];
    float4 o;
    o.x = jv * wv.x; o.y = jv * wv.y; o.z = jv * wv.z; o.w = jv * wv.w;
    *(float4*)&cw[(size_t)v * NKJ + kj0] = o;
}

// AT[a][v][r]: v-major transposed stack of {posedirs rows, shapedirs rows, v_template, ones}
__global__ void k_at(const float* __restrict__ pd, const float* __restrict__ sd,
                     const float* __restrict__ vt, float* __restrict__ AT) {
    int idx = blockIdx.x * 256 + threadIdx.x;
    const int TOT = 3 * NV * ATP;
    if (idx >= TOT) return;
    int a = idx / (NV * ATP);
    int rem = idx - a * (NV * ATP);
    int v = rem / ATP;
    int r = rem - v * ATP;
    float val;
    if (r < NPOSE)              val = pd[r * VSTR + 3 * v + a];
    else if (r < NPOSE + NBETA) val = sd[(r - NPOSE) * VSTR + 3 * v + a];
    else if (r == 217)          val = vt[3 * v + a];
    else if (r == 218)          val = 1.0f;
    else                        val = 0.0f;
    AT[idx] = val;
}

// JS[row<10][j][a] = sum_v Jreg[v,j]*shapedirs[row,3v+a];  JS[10][j][a] = sum_v Jreg[v,j]*vt[v,a]
__global__ void k_js(const float* __restrict__ Jreg, const float* __restrict__ sd,
                     const float* __restrict__ vt, float* __restrict__ JS) {
    int row = blockIdx.x / NJ;
    int j = blockIdx.x - row * NJ;
    int lane = threadIdx.x;
    const float* src = (row < NBETA) ? (sd + (size_t)row * VSTR) : vt;
    float a0 = 0.f, a1 = 0.f, a2 = 0.f;
    for (int v = lane; v < NV; v += 64) {
        float jrv = Jreg[v * NJ + j];
        a0 += jrv * src[3 * v];
        a1 += jrv * src[3 * v + 1];
        a2 += jrv * src[3 * v + 2];
    }
    for (int off = 32; off; off >>= 1) {
        a0 += __shfl_down(a0, off);
        a1 += __shfl_down(a1, off);
        a2 += __shfl_down(a2, off);
    }
    if (lane == 0) {
        JS[(row * NJ + j) * 3 + 0] = a0;
        JS[(row * NJ + j) * 3 + 1] = a1;
        JS[(row * NJ + j) * 3 + 2] = a2;
    }
}

// per-batch: Rodrigues, pose_feature -> coefT, joint locations, kinematic chain -> A (rot+trans)
__global__ __launch_bounds__(64) void k_pose(const float* __restrict__ beta,
                                             const float* __restrict__ theta,
                                             const float* __restrict__ JS,
                                             float* __restrict__ coefT,
                                             float* __restrict__ Aw) {
    int n = blockIdx.x;
    int tid = threadIdx.x;
    __shared__ float Rs[24][9];
    __shared__ float Jl[24][3];
    __shared__ float G[24][12];

    if (tid < NJ) {
        int j = tid;
        float x = theta[n * 72 + j * 3 + 0];
        float y = theta[n * 72 + j * 3 + 1];
        float z = theta[n * 72 + j * 3 + 2];
        float ang = sqrtf(x * x + y * y + z * z + 1e-8f);
        float inv = 1.0f / ang;
        float rx = x * inv, ry = y * inv, rz = z * inv;
        float ct = cosf(ang), st = sinf(ang), oc = 1.0f - ct;
        float R[9];
        R[0] = ct + oc * rx * rx;  R[1] = -st * rz + oc * rx * ry; R[2] =  st * ry + oc * rx * rz;
        R[3] =  st * rz + oc * ry * rx; R[4] = ct + oc * ry * ry;  R[5] = -st * rx + oc * ry * rz;
        R[6] = -st * ry + oc * rz * rx; R[7] =  st * rx + oc * rz * ry; R[8] = ct + oc * rz * rz;
#pragma unroll
        for (int e = 0; e < 9; e++) Rs[j][e] = R[e];
        if (j >= 1) {
#pragma unroll
            for (int e = 0; e < 9; e++)
                coefT[(size_t)((j - 1) * 9 + e) * NB + n] =
                    R[e] - ((e == 0 || e == 4 || e == 8) ? 1.0f : 0.0f);
        }
    }
    if (tid < NBETA) coefT[(size_t)(NPOSE + tid) * NB + n] = beta[n * NBETA + tid];
    if (tid == 63)   coefT[(size_t)217 * NB + n] = 1.0f;
    __syncthreads();

    for (int idx = tid; idx < 72; idx += 64) {
        int j = idx / 3, a = idx - j * 3;
        float acc = JS[(NBETA * NJ + j) * 3 + a];
#pragma unroll
        for (int b = 0; b < NBETA; b++) acc += beta[n * NBETA + b] * JS[(b * NJ + j) * 3 + a];
        Jl[j][a] = acc;
    }
    __syncthreads();

    if (tid < 12) {
        int r = tid >> 2, cc = tid & 3;
        G[0][tid] = (cc < 3) ? Rs[0][r * 3 + cc] : Jl[0][r];
    }
    __syncthreads();

    const int PAR[24] = {0,0,0,0,1,2,3,4,5,6,7,8,9,9,9,12,13,14,16,17,18,19,20,21};
#pragma unroll
    for (int i = 1; i < NJ; i++) {
        int p = PAR[i];
        if (tid < 12) {
            int r = tid >> 2, cc = tid & 3;
            float g0 = G[p][r * 4 + 0], g1 = G[p][r * 4 + 1];
            float g2 = G[p][r * 4 + 2], g3 = G[p][r * 4 + 3];
            float val;
            if (cc < 3) {
                val = g0 * Rs[i][cc] + g1 * Rs[i][3 + cc] + g2 * Rs[i][6 + cc];
            } else {
                float t0 = Jl[i][0] - Jl[p][0];
                float t1 = Jl[i][1] - Jl[p][1];
                float t2 = Jl[i][2] - Jl[p][2];
                val = g0 * t0 + g1 * t1 + g2 * t2 + g3;
            }
            G[i][tid] = val;
        }
        __syncthreads();
    }

    for (int idx = tid; idx < 288; idx += 64) {
        int j = idx / 12, e = idx - j * 12;
        float val;
        if (e < 9) {
            int r = e / 3, cc = e - 3 * (e / 3);
            val = G[j][r * 4 + cc];
        } else {
            int r = e - 9;
            val = G[j][r * 4 + 3] -
                  (G[j][r * 4 + 0] * Jl[j][0] + G[j][r * 4 + 1] * Jl[j][1] +
                   G[j][r * 4 + 2] * Jl[j][2]);
        }
        Aw[(size_t)n * 288 + idx] = val;
    }
}

// OUT[r][a*456+col] += sum_v AT[a][v][r] * c[v][col]   (split-K x16, 64x64x32 tiles)
__global__ __launch_bounds__(256) void k_gemmP(const float* __restrict__ AT,
                                               const float* __restrict__ cw,
                                               float* __restrict__ OUTB) {
    int bid = blockIdx.x;
    int mt = bid & 3;  bid >>= 2;
    int nt = bid & 7;  bid >>= 3;
    int a = bid % 3;
    int ks = bid / 3;
    const int mb = mt * 64, nb = nt * 64;
    int v0 = ks * CHP, v1 = min(NV, v0 + CHP);
    __shared__ float As[32][64];
    __shared__ float Bs[32][64];
    int tid = threadIdx.x;
    int tm = tid & 15, tn = tid >> 4;
    float acc[4][4] = {};
    const float* ATa = AT + (size_t)a * NV * ATP;
    for (int vb = v0; vb < v1; vb += 32) {
#pragma unroll
        for (int i = 0; i < 8; i++) {
            int idx = tid + i * 256;
            int kk = idx >> 6, m = idx & 63;
            int v = vb + kk;
            int r = mb + m;
            As[kk][m] = (v < v1 && r < ATP) ? ATa[(size_t)v * ATP + r] : 0.f;
            int col = nb + m;
            Bs[kk][m] = (v < v1 && col < NKJ) ? cw[(size_t)v * NKJ + col] : 0.f;
        }
        __syncthreads();
#pragma unroll
        for (int kk = 0; kk < 32; kk++) {
            float4 av = *(const float4*)&As[kk][tm * 4];
            float4 bv = *(const float4*)&Bs[kk][tn * 4];
            float am[4] = {av.x, av.y, av.z, av.w};
            float bn[4] = {bv.x, bv.y, bv.z, bv.w};
#pragma unroll
            for (int i = 0; i < 4; i++)
#pragma unroll
                for (int j = 0; j < 4; j++) acc[i][j] += am[i] * bn[j];
        }
        __syncthreads();
    }
#pragma unroll
    for (int i = 0; i < 4; i++) {
        int r = mb + tm * 4 + i;
        if (r >= AR) continue;
#pragma unroll
        for (int j = 0; j < 4; j++) {
            int col = nb + tn * 4 + j;
            if (col < NKJ) atomicAdd(&OUTB[(size_t)r * NCOL + a * NKJ + col], acc[i][j]);
        }
    }
}

// M[n][col] = sum_r coefT[r][n] * OUT[r][col]   (1024 x 1368 x 218), 32x64 tiles for occupancy
__global__ __launch_bounds__(256) void k_gemmM(const float* __restrict__ coefT,
                                               const float* __restrict__ OUTB,
                                               float* __restrict__ M) {
    int bid = blockIdx.x;
    int mt = bid & 31, nt = bid >> 5;   // 32 x 22
    int mb = mt * 32, nb = nt * 64;
    __shared__ float Cs[32][32];
    __shared__ float Bs[32][64];
    int tid = threadIdx.x;
    int tm = tid & 15, tn = tid >> 4;
    float acc[2][4] = {};
    for (int kb = 0; kb < KR; kb += 32) {
#pragma unroll
        for (int p = 0; p < 4; p++) {
            int idx = tid + p * 256;
            int kk = idx >> 5, nl = idx & 31;
            int r = kb + kk;
            Cs[kk][nl] = (r < KR) ? coefT[(size_t)r * NB + mb + nl] : 0.f;
        }
#pragma unroll
        for (int p = 0; p < 8; p++) {
            int idx = tid + p * 256;
            int kk = idx >> 6, m = idx & 63;
            int r = kb + kk;
            int col = nb + m;
            Bs[kk][m] = (r < KR && col < NCOL) ? OUTB[(size_t)r * NCOL + col] : 0.f;
        }
        __syncthreads();
#pragma unroll
        for (int kk = 0; kk < 32; kk++) {
            float2 cv = *(const float2*)&Cs[kk][tm * 2];
            float4 bv = *(const float4*)&Bs[kk][tn * 4];
            float cm[2] = {cv.x, cv.y};
            float bn[4] = {bv.x, bv.y, bv.z, bv.w};
#pragma unroll
            for (int i = 0; i < 2; i++)
#pragma unroll
                for (int j = 0; j < 4; j++) acc[i][j] += cm[i] * bn[j];
        }
        __syncthreads();
    }
#pragma unroll
    for (int i = 0; i < 2; i++) {
        int n = mb + tm * 2 + i;
#pragma unroll
        for (int j = 0; j < 4; j++) {
            int col = nb + tn * 4 + j;
            if (col < NCOL) M[(size_t)n * NCOL + col] = acc[i][j];
        }
    }
}

// joints[n,k,a] = sum_j R_A[n,j,a,:].m[n,k,j,:] + s[k,j]*t_A[n,j,a]
__global__ void k_joints(const float* __restrict__ M, const float* __restrict__ Aw,
                         const float* __restrict__ OUTB, float* __restrict__ out) {
    int idx = blockIdx.x * 256 + threadIdx.x;
    if (idx >= NB * NK) return;
    int n = idx / NK, k = idx - n * NK;
    const float* A = Aw + (size_t)n * 288;
    const float* Mn = M + (size_t)n * NCOL;
    float o0 = 0.f, o1 = 0.f, o2 = 0.f;
#pragma unroll
    for (int j = 0; j < NJ; j++) {
        int kj = k * NJ + j;
        float m0 = Mn[kj];
        float m1 = Mn[NKJ + kj];
        float m2 = Mn[2 * NKJ + kj];
        float s = OUTB[(size_t)218 * NCOL + kj];
        const float* Aj = A + j * 12;
        o0 += Aj[0] * m0 + Aj[1] * m1 + Aj[2] * m2 + s * Aj[9];
        o1 += Aj[3] * m0 + Aj[4] * m1 + Aj[5] * m2 + s * Aj[10];
        o2 += Aj[6] * m0 + Aj[7] * m1 + Aj[8] * m2 + s * Aj[11];
    }
    out[idx * 3 + 0] = o0;
    out[idx * 3 + 1] = o1;
    out[idx * 3 + 2] = o2;
}

extern "C" void kernel_launch(void* const* d_in, const int* in_sizes, int n_in,
                              void* d_out, int out_size, void* d_ws, size_t ws_size,
                              hipStream_t stream) {
    const float* beta  = (const float*)d_in[0];
    const float* theta = (const float*)d_in[1];
    const float* vt    = (const float*)d_in[2];
    const float* sd    = (const float*)d_in[3];
    const float* Jreg  = (const float*)d_in[4];
    const float* pd    = (const float*)d_in[5];
    const float* w     = (const float*)d_in[6];
    const float* jr    = (const float*)d_in[7];

    float* ws    = (float*)d_ws;
    float* cw    = ws + OFF_C;
    float* AT    = ws + OFF_AT;
    float* OUTB  = ws + OFF_OUT;
    float* coefT = ws + OFF_COEF;
    float* Aw    = ws + OFF_AW;
    float* JS    = ws + OFF_JS;
    float* M     = ws + OFF_M;
    float* out   = (float*)d_out;

    hipMemsetAsync(OUTB, 0, SZ_OUT * sizeof(float), stream);
    k_cw<<<(NV * (NKJ / 4) + 255) / 256, 256, 0, stream>>>(jr, w, cw);
    k_at<<<(3 * NV * ATP + 255) / 256, 256, 0, stream>>>(pd, sd, vt, AT);
    k_js<<<11 * NJ, 64, 0, stream>>>(Jreg, sd, vt, JS);
    k_pose<<<NB, 64, 0, stream>>>(beta, theta, JS, coefT, Aw);
    k_gemmP<<<4 * 8 * 3 * KSPLIT, 256, 0, stream>>>(AT, cw, OUTB);
    k_gemmM<<<32 * 22, 256, 0, stream>>>(coefT, OUTB, M);
    k_joints<<<(NB * NK + 255) / 256, 256, 0, stream>>>(M, Aw, OUTB, out);
}

// Round 5
// 259.399 us; speedup vs baseline: 1.6805x; 1.6805x over previous
//
#include <hip/hip_runtime.h>

#define NB 1024
#define NV 6890
#define VP 6912       // NV padded to mult of 32
#define VP4 1728      // VP/4
#define NJ 24
#define NBETA 10
#define NPOSE 207
#define NK 19
#define NKJ 456       // 19*24
#define NCOL 1368     // 3*456
#define KR 218        // coef rows: 207 pose + 10 beta + 1 const
#define AR 219        // GEMM A rows: KR + s-row (ones)
#define VSTR 20670    // 3*NV
#define KSPLIT 8
#define KCH 864       // VP/KSPLIT

typedef __attribute__((ext_vector_type(8))) short bf16x8;
typedef __attribute__((ext_vector_type(4))) float f32x4;

// ---- workspace layout ----
// ushort region: ATH/ATL [3][AR][VP], cwH/cwL [NKJ][VP]
#define N_AT   ((size_t)3*AR*VP)      // 4,541,184 ushorts
#define N_CW   ((size_t)NKJ*VP)       // 3,151,872 ushorts
#define USH_TOTAL (2*N_AT + 2*N_CW)   // 15,386,112 ushorts = 30.77 MB
// float region follows
#define SZ_OUT   ((size_t)AR*NCOL)    // 299,592
#define SZ_COEF  ((size_t)KR*NB)      // 223,232
#define SZ_AW    ((size_t)NB*288)     // 294,912
#define SZ_JS    (11ull*24*3)         // 792
#define SZ_M     ((size_t)NB*NCOL)    // 1,400,832
// total ≈ 39.65 MB

__device__ inline void bf_split(float x, unsigned short& h, unsigned short& l) {
    unsigned u = __float_as_uint(x);
    h = (unsigned short)(u >> 16);
    float hf = __uint_as_float((unsigned)h << 16);
    float lf = x - hf;
    l = (unsigned short)(__float_as_uint(lf) >> 16);
}

// ATH/ATL[a][r][v]: bf16 hi/lo of {posedirs,shapedirs,v_template,ones} transposed, v-contiguous
__global__ void k_at2(const float* __restrict__ pd, const float* __restrict__ sd,
                      const float* __restrict__ vt,
                      unsigned short* __restrict__ ATH, unsigned short* __restrict__ ATL) {
    int idx = blockIdx.x * 256 + threadIdx.x;
    const int TOT = 3 * AR * VP4;
    if (idx >= TOT) return;
    int a = idx / (AR * VP4);
    int rem = idx - a * (AR * VP4);
    int r = rem / VP4;
    int v0 = (rem - r * VP4) * 4;
    ushort4 h, l;
    unsigned short hh[4], ll[4];
#pragma unroll
    for (int e = 0; e < 4; e++) {
        int v = v0 + e;
        float val = 0.f;
        if (v < NV) {
            if (r < NPOSE)        val = pd[r * VSTR + 3 * v + a];
            else if (r < 217)     val = sd[(r - NPOSE) * VSTR + 3 * v + a];
            else if (r == 217)    val = vt[3 * v + a];
            else                  val = 1.0f;   // r == 218: ones row
        }
        bf_split(val, hh[e], ll[e]);
    }
    h.x = hh[0]; h.y = hh[1]; h.z = hh[2]; h.w = hh[3];
    l.x = ll[0]; l.y = ll[1]; l.z = ll[2]; l.w = ll[3];
    size_t off = ((size_t)a * AR + r) * VP + v0;
    *(ushort4*)&ATH[off] = h;
    *(ushort4*)&ATL[off] = l;
}

// cwH/cwL[col][v] = bf16 hi/lo of jr[v,k]*w[v,j], v-contiguous
__global__ void k_cw2(const float* __restrict__ jr, const float* __restrict__ w,
                      unsigned short* __restrict__ cwH, unsigned short* __restrict__ cwL) {
    int idx = blockIdx.x * 256 + threadIdx.x;
    const int TOT = NKJ * VP4;
    if (idx >= TOT) return;
    int col = idx / VP4;
    int v0 = (idx - col * VP4) * 4;
    int k = col / NJ, j = col - k * NJ;
    ushort4 h, l;
    unsigned short hh[4], ll[4];
#pragma unroll
    for (int e = 0; e < 4; e++) {
        int v = v0 + e;
        float val = (v < NV) ? jr[v * NK + k] * w[v * NJ + j] : 0.f;
        bf_split(val, hh[e], ll[e]);
    }
    h.x = hh[0]; h.y = hh[1]; h.z = hh[2]; h.w = hh[3];
    l.x = ll[0]; l.y = ll[1]; l.z = ll[2]; l.w = ll[3];
    size_t off = (size_t)col * VP + v0;
    *(ushort4*)&cwH[off] = h;
    *(ushort4*)&cwL[off] = l;
}

// JS[row<10][j][a] = sum_v Jreg[v,j]*shapedirs[row,3v+a];  JS[10][j][a] = sum_v Jreg[v,j]*vt[v,a]
__global__ void k_js(const float* __restrict__ Jreg, const float* __restrict__ sd,
                     const float* __restrict__ vt, float* __restrict__ JS) {
    int row = blockIdx.x / NJ;
    int j = blockIdx.x - row * NJ;
    int lane = threadIdx.x;
    const float* src = (row < NBETA) ? (sd + (size_t)row * VSTR) : vt;
    float a0 = 0.f, a1 = 0.f, a2 = 0.f;
    for (int v = lane; v < NV; v += 64) {
        float jrv = Jreg[v * NJ + j];
        a0 += jrv * src[3 * v];
        a1 += jrv * src[3 * v + 1];
        a2 += jrv * src[3 * v + 2];
    }
    for (int off = 32; off; off >>= 1) {
        a0 += __shfl_down(a0, off);
        a1 += __shfl_down(a1, off);
        a2 += __shfl_down(a2, off);
    }
    if (lane == 0) {
        JS[(row * NJ + j) * 3 + 0] = a0;
        JS[(row * NJ + j) * 3 + 1] = a1;
        JS[(row * NJ + j) * 3 + 2] = a2;
    }
}

// per-batch: Rodrigues, pose_feature -> coefT, joint locations, kinematic chain -> A (rot+trans)
__global__ __launch_bounds__(64) void k_pose(const float* __restrict__ beta,
                                             const float* __restrict__ theta,
                                             const float* __restrict__ JS,
                                             float* __restrict__ coefT,
                                             float* __restrict__ Aw) {
    int n = blockIdx.x;
    int tid = threadIdx.x;
    __shared__ float Rs[24][9];
    __shared__ float Jl[24][3];
    __shared__ float G[24][12];

    if (tid < NJ) {
        int j = tid;
        float x = theta[n * 72 + j * 3 + 0];
        float y = theta[n * 72 + j * 3 + 1];
        float z = theta[n * 72 + j * 3 + 2];
        float ang = sqrtf(x * x + y * y + z * z + 1e-8f);
        float inv = 1.0f / ang;
        float rx = x * inv, ry = y * inv, rz = z * inv;
        float ct = cosf(ang), st = sinf(ang), oc = 1.0f - ct;
        float R[9];
        R[0] = ct + oc * rx * rx;  R[1] = -st * rz + oc * rx * ry; R[2] =  st * ry + oc * rx * rz;
        R[3] =  st * rz + oc * ry * rx; R[4] = ct + oc * ry * ry;  R[5] = -st * rx + oc * ry * rz;
        R[6] = -st * ry + oc * rz * rx; R[7] =  st * rx + oc * rz * ry; R[8] = ct + oc * rz * rz;
#pragma unroll
        for (int e = 0; e < 9; e++) Rs[j][e] = R[e];
        if (j >= 1) {
#pragma unroll
            for (int e = 0; e < 9; e++)
                coefT[(size_t)((j - 1) * 9 + e) * NB + n] =
                    R[e] - ((e == 0 || e == 4 || e == 8) ? 1.0f : 0.0f);
        }
    }
    if (tid < NBETA) coefT[(size_t)(NPOSE + tid) * NB + n] = beta[n * NBETA + tid];
    if (tid == 63)   coefT[(size_t)217 * NB + n] = 1.0f;
    __syncthreads();

    for (int idx = tid; idx < 72; idx += 64) {
        int j = idx / 3, a = idx - j * 3;
        float acc = JS[(NBETA * NJ + j) * 3 + a];
#pragma unroll
        for (int b = 0; b < NBETA; b++) acc += beta[n * NBETA + b] * JS[(b * NJ + j) * 3 + a];
        Jl[j][a] = acc;
    }
    __syncthreads();

    if (tid < 12) {
        int r = tid >> 2, cc = tid & 3;
        G[0][tid] = (cc < 3) ? Rs[0][r * 3 + cc] : Jl[0][r];
    }
    __syncthreads();

    const int PAR[24] = {0,0,0,0,1,2,3,4,5,6,7,8,9,9,9,12,13,14,16,17,18,19,20,21};
#pragma unroll
    for (int i = 1; i < NJ; i++) {
        int p = PAR[i];
        if (tid < 12) {
            int r = tid >> 2, cc = tid & 3;
            float g0 = G[p][r * 4 + 0], g1 = G[p][r * 4 + 1];
            float g2 = G[p][r * 4 + 2], g3 = G[p][r * 4 + 3];
            float val;
            if (cc < 3) {
                val = g0 * Rs[i][cc] + g1 * Rs[i][3 + cc] + g2 * Rs[i][6 + cc];
            } else {
                float t0 = Jl[i][0] - Jl[p][0];
                float t1 = Jl[i][1] - Jl[p][1];
                float t2 = Jl[i][2] - Jl[p][2];
                val = g0 * t0 + g1 * t1 + g2 * t2 + g3;
            }
            G[i][tid] = val;
        }
        __syncthreads();
    }

    for (int idx = tid; idx < 288; idx += 64) {
        int j = idx / 12, e = idx - j * 12;
        float val;
        if (e < 9) {
            int r = e / 3, cc = e - 3 * (e / 3);
            val = G[j][r * 4 + cc];
        } else {
            int r = e - 9;
            val = G[j][r * 4 + 3] -
                  (G[j][r * 4 + 0] * Jl[j][0] + G[j][r * 4 + 1] * Jl[j][1] +
                   G[j][r * 4 + 2] * Jl[j][2]);
        }
        Aw[(size_t)n * 288 + idx] = val;
    }
}

// MFMA bf16 hi/lo GEMM: OUT[r][a*456+col] += sum_v AT[a][r][v]*cw[col][v]
// 64x64 tile, 4 waves (2x2), each wave 2x2 mfma_f32_16x16x32_bf16, split-K x8 + atomics.
__global__ __launch_bounds__(256) void k_gemmP(const unsigned short* __restrict__ ATH,
                                               const unsigned short* __restrict__ ATL,
                                               const unsigned short* __restrict__ cwH,
                                               const unsigned short* __restrict__ cwL,
                                               float* __restrict__ OUTB) {
    int bid = blockIdx.x;
    int mt = bid & 3;
    int nt = (bid >> 2) & 7;
    int a  = (bid >> 5) % 3;
    int ks = bid / 96;
    int mb = mt * 64, nb = nt * 64;

    __shared__ __align__(16) short As[2][64][40];  // [hi/lo][r][v], pad 32->40 (2-way max)
    __shared__ __align__(16) short Bs[2][64][40];  // [hi/lo][col][v]

    int tid = threadIdx.x;
    int row = tid >> 2, ch = tid & 3;      // staging: 64 rows x 4 chunks of 8 bf16
    int lane = tid & 63, wv = tid >> 6;
    int wm = wv >> 1, wn = wv & 1;         // wave 2x2 grid -> 32x32 per wave
    int lr = lane & 15, lc = lane >> 4;

    bool okA = (mb + row) < AR;
    bool okB = (nb + row) < NKJ;
    const unsigned short* pAH = ATH + ((size_t)a * AR + (okA ? mb + row : 0)) * VP + ch * 8;
    const unsigned short* pAL = ATL + ((size_t)a * AR + (okA ? mb + row : 0)) * VP + ch * 8;
    const unsigned short* pBH = cwH + (size_t)(okB ? nb + row : 0) * VP + ch * 8;
    const unsigned short* pBL = cwL + (size_t)(okB ? nb + row : 0) * VP + ch * 8;

    f32x4 acc[2][2] = {};

    for (int s = 0; s < KCH / 32; ++s) {
        int vb = ks * KCH + s * 32;
        int4 z; z.x = z.y = z.z = z.w = 0;
        int4 vah = okA ? *(const int4*)(pAH + vb) : z;
        int4 valo = okA ? *(const int4*)(pAL + vb) : z;
        int4 vbh = okB ? *(const int4*)(pBH + vb) : z;
        int4 vblo = okB ? *(const int4*)(pBL + vb) : z;
        __syncthreads();
        *(int4*)&As[0][row][ch * 8] = vah;
        *(int4*)&As[1][row][ch * 8] = valo;
        *(int4*)&Bs[0][row][ch * 8] = vbh;
        *(int4*)&Bs[1][row][ch * 8] = vblo;
        __syncthreads();

        bf16x8 aH[2], aL[2], bH[2], bL[2];
#pragma unroll
        for (int t = 0; t < 2; ++t) {
            aH[t] = *(const bf16x8*)&As[0][wm * 32 + t * 16 + lr][lc * 8];
            aL[t] = *(const bf16x8*)&As[1][wm * 32 + t * 16 + lr][lc * 8];
            bH[t] = *(const bf16x8*)&Bs[0][wn * 32 + t * 16 + lr][lc * 8];
            bL[t] = *(const bf16x8*)&Bs[1][wn * 32 + t * 16 + lr][lc * 8];
        }
#pragma unroll
        for (int mi = 0; mi < 2; ++mi)
#pragma unroll
            for (int ni = 0; ni < 2; ++ni) {
                acc[mi][ni] = __builtin_amdgcn_mfma_f32_16x16x32_bf16(aH[mi], bH[ni], acc[mi][ni], 0, 0, 0);
                acc[mi][ni] = __builtin_amdgcn_mfma_f32_16x16x32_bf16(aH[mi], bL[ni], acc[mi][ni], 0, 0, 0);
                acc[mi][ni] = __builtin_amdgcn_mfma_f32_16x16x32_bf16(aL[mi], bH[ni], acc[mi][ni], 0, 0, 0);
            }
    }

#pragma unroll
    for (int mi = 0; mi < 2; ++mi)
#pragma unroll
        for (int ni = 0; ni < 2; ++ni)
#pragma unroll
            for (int q = 0; q < 4; ++q) {
                int r = mb + wm * 32 + mi * 16 + lc * 4 + q;   // D row = (lane>>4)*4+reg [m89]
                int c = nb + wn * 32 + ni * 16 + lr;           // D col = lane&15
                if (r < AR && c < NKJ)
                    atomicAdd(&OUTB[(size_t)r * NCOL + a * NKJ + c], acc[mi][ni][q]);
            }
}

// M[n][col] = sum_r coefT[r][n] * OUT[r][col]   (1024 x 1368 x 218) — round-0 measured version
__global__ __launch_bounds__(256) void k_gemmM(const float* __restrict__ coefT,
                                               const float* __restrict__ OUTB,
                                               float* __restrict__ M) {
    int bid = blockIdx.x;
    int mt = bid % 16, nt = bid / 16;
    int mb = mt * 64, nb = nt * 64;
    __shared__ float Cs[32][64];
    __shared__ float Bs[32][64];
    int tid = threadIdx.x;
    int tm = tid & 15, tn = tid >> 4;
    float acc[4][4] = {};
    for (int kb = 0; kb < KR; kb += 32) {
#pragma unroll
        for (int i = 0; i < 8; i++) {
            int idx = tid + i * 256;
            int kk = idx >> 6, m = idx & 63;
            int r = kb + kk;
            Cs[kk][m] = (r < KR) ? coefT[(size_t)r * NB + mb + m] : 0.f;
            int col = nb + m;
            Bs[kk][m] = (r < KR && col < NCOL) ? OUTB[(size_t)r * NCOL + col] : 0.f;
        }
        __syncthreads();
#pragma unroll
        for (int kk = 0; kk < 32; kk++) {
            float4 av = *(const float4*)&Cs[kk][tm * 4];
            float4 bv = *(const float4*)&Bs[kk][tn * 4];
            float am[4] = {av.x, av.y, av.z, av.w};
            float bn[4] = {bv.x, bv.y, bv.z, bv.w};
#pragma unroll
            for (int i = 0; i < 4; i++)
#pragma unroll
                for (int j = 0; j < 4; j++) acc[i][j] += am[i] * bn[j];
        }
        __syncthreads();
    }
#pragma unroll
    for (int i = 0; i < 4; i++) {
        int n = mb + tm * 4 + i;
#pragma unroll
        for (int j = 0; j < 4; j++) {
            int col = nb + tn * 4 + j;
            if (col < NCOL) M[(size_t)n * NCOL + col] = acc[i][j];
        }
    }
}

// joints[n,k,a] = sum_j R_A[n,j,a,:].m[n,k,j,:] + s[k,j]*t_A[n,j,a]
__global__ void k_joints(const float* __restrict__ M, const float* __restrict__ Aw,
                         const float* __restrict__ OUTB, float* __restrict__ out) {
    int idx = blockIdx.x * 256 + threadIdx.x;
    if (idx >= NB * NK) return;
    int n = idx / NK, k = idx - n * NK;
    const float* A = Aw + (size_t)n * 288;
    const float* Mn = M + (size_t)n * NCOL;
    float o0 = 0.f, o1 = 0.f, o2 = 0.f;
#pragma unroll
    for (int j = 0; j < NJ; j++) {
        int kj = k * NJ + j;
        float m0 = Mn[kj];
        float m1 = Mn[NKJ + kj];
        float m2 = Mn[2 * NKJ + kj];
        float s = OUTB[(size_t)218 * NCOL + kj];
        const float* Aj = A + j * 12;
        o0 += Aj[0] * m0 + Aj[1] * m1 + Aj[2] * m2 + s * Aj[9];
        o1 += Aj[3] * m0 + Aj[4] * m1 + Aj[5] * m2 + s * Aj[10];
        o2 += Aj[6] * m0 + Aj[7] * m1 + Aj[8] * m2 + s * Aj[11];
    }
    out[idx * 3 + 0] = o0;
    out[idx * 3 + 1] = o1;
    out[idx * 3 + 2] = o2;
}

extern "C" void kernel_launch(void* const* d_in, const int* in_sizes, int n_in,
                              void* d_out, int out_size, void* d_ws, size_t ws_size,
                              hipStream_t stream) {
    const float* beta  = (const float*)d_in[0];
    const float* theta = (const float*)d_in[1];
    const float* vt    = (const float*)d_in[2];
    const float* sd    = (const float*)d_in[3];
    const float* Jreg  = (const float*)d_in[4];
    const float* pd    = (const float*)d_in[5];
    const float* w     = (const float*)d_in[6];
    const float* jr    = (const float*)d_in[7];

    unsigned short* ush = (unsigned short*)d_ws;
    unsigned short* ATH = ush;
    unsigned short* ATL = ATH + N_AT;
    unsigned short* cwH = ATL + N_AT;
    unsigned short* cwL = cwH + N_CW;
    float* fbase = (float*)(ush + USH_TOTAL);
    float* OUTB  = fbase;
    float* coefT = OUTB + SZ_OUT;
    float* Aw    = coefT + SZ_COEF;
    float* JS    = Aw + SZ_AW;
    float* M     = JS + SZ_JS;
    float* out   = (float*)d_out;

    hipMemsetAsync(OUTB, 0, SZ_OUT * sizeof(float), stream);
    k_at2<<<(3 * AR * VP4 + 255) / 256, 256, 0, stream>>>(pd, sd, vt, ATH, ATL);
    k_cw2<<<(NKJ * VP4 + 255) / 256, 256, 0, stream>>>(jr, w, cwH, cwL);
    k_js<<<11 * NJ, 64, 0, stream>>>(Jreg, sd, vt, JS);
    k_pose<<<NB, 64, 0, stream>>>(beta, theta, JS, coefT, Aw);
    k_gemmP<<<4 * 8 * 3 * KSPLIT, 256, 0, stream>>>(ATH, ATL, cwH, cwL, OUTB);
    k_gemmM<<<16 * 22, 256, 0, stream>>>(coefT, OUTB, M);
    k_joints<<<(NB * NK + 255) / 256, 256, 0, stream>>>(M, Aw, OUTB, out);
}

// Round 6
// 236.959 us; speedup vs baseline: 1.8396x; 1.0947x over previous
//
#include <hip/hip_runtime.h>

#define NB 1024
#define NV 6890
#define VP 6912       // NV padded to mult of 32
#define VP4 1728      // VP/4
#define NJ 24
#define NBETA 10
#define NPOSE 207
#define NK 19
#define NKJ 456       // 19*24
#define NCOL 1368     // 3*456
#define KR 218        // coef rows: 207 pose + 10 beta + 1 const
#define AR 219        // GEMM A rows: KR + s-row (ones)
#define VSTR 20670    // 3*NV
#define KSPLIT 8
#define KCH 864       // VP/KSPLIT

typedef __attribute__((ext_vector_type(8))) short bf16x8;
typedef __attribute__((ext_vector_type(4))) float f32x4;

// ---- workspace layout ----
#define N_AT   ((size_t)3*AR*VP)      // 4,541,184 ushorts
#define N_CW   ((size_t)NKJ*VP)       // 3,151,872 ushorts
#define USH_TOTAL (2*N_AT + 2*N_CW)
#define SZ_OUT   ((size_t)AR*NCOL)    // 299,592
#define SZ_COEF  ((size_t)KR*NB)      // 223,232
#define SZ_AW    ((size_t)NB*288)     // 294,912
#define SZ_JS    (11ull*24*3)         // 792
#define SZ_M     ((size_t)NB*NCOL)    // 1,400,832

__device__ inline void bf_split(float x, unsigned short& h, unsigned short& l) {
    unsigned u = __float_as_uint(x);
    h = (unsigned short)(u >> 16);
    float hf = __uint_as_float((unsigned)h << 16);
    float lf = x - hf;
    l = (unsigned short)(__float_as_uint(lf) >> 16);
}

// ATH/ATL[a][r][v]: bf16 hi/lo of {posedirs,shapedirs,v_template,ones} transposed, v-contiguous
__global__ void k_at2(const float* __restrict__ pd, const float* __restrict__ sd,
                      const float* __restrict__ vt,
                      unsigned short* __restrict__ ATH, unsigned short* __restrict__ ATL) {
    int idx = blockIdx.x * 256 + threadIdx.x;
    const int TOT = 3 * AR * VP4;
    if (idx >= TOT) return;
    int a = idx / (AR * VP4);
    int rem = idx - a * (AR * VP4);
    int r = rem / VP4;
    int v0 = (rem - r * VP4) * 4;
    ushort4 h, l;
    unsigned short hh[4], ll[4];
#pragma unroll
    for (int e = 0; e < 4; e++) {
        int v = v0 + e;
        float val = 0.f;
        if (v < NV) {
            if (r < NPOSE)        val = pd[r * VSTR + 3 * v + a];
            else if (r < 217)     val = sd[(r - NPOSE) * VSTR + 3 * v + a];
            else if (r == 217)    val = vt[3 * v + a];
            else                  val = 1.0f;   // r == 218: ones row
        }
        bf_split(val, hh[e], ll[e]);
    }
    h.x = hh[0]; h.y = hh[1]; h.z = hh[2]; h.w = hh[3];
    l.x = ll[0]; l.y = ll[1]; l.z = ll[2]; l.w = ll[3];
    size_t off = ((size_t)a * AR + r) * VP + v0;
    *(ushort4*)&ATH[off] = h;
    *(ushort4*)&ATL[off] = l;
}

// cwH/cwL[col][v] = bf16 hi/lo of jr[v,k]*w[v,j], v-contiguous
__global__ void k_cw2(const float* __restrict__ jr, const float* __restrict__ w,
                      unsigned short* __restrict__ cwH, unsigned short* __restrict__ cwL) {
    int idx = blockIdx.x * 256 + threadIdx.x;
    const int TOT = NKJ * VP4;
    if (idx >= TOT) return;
    int col = idx / VP4;
    int v0 = (idx - col * VP4) * 4;
    int k = col / NJ, j = col - k * NJ;
    ushort4 h, l;
    unsigned short hh[4], ll[4];
#pragma unroll
    for (int e = 0; e < 4; e++) {
        int v = v0 + e;
        float val = (v < NV) ? jr[v * NK + k] * w[v * NJ + j] : 0.f;
        bf_split(val, hh[e], ll[e]);
    }
    h.x = hh[0]; h.y = hh[1]; h.z = hh[2]; h.w = hh[3];
    l.x = ll[0]; l.y = ll[1]; l.z = ll[2]; l.w = ll[3];
    size_t off = (size_t)col * VP + v0;
    *(ushort4*)&cwH[off] = h;
    *(ushort4*)&cwL[off] = l;
}

// JS[row][j][a] += sum_v Jreg[v,j]*src_row[v,a]; split-K over v, 72 reg accumulators/thread,
// wave shuffle-reduce + atomics. rows 0..9 = shapedirs, row 10 = v_template.
__global__ __launch_bounds__(256) void k_js2(const float* __restrict__ Jreg,
                                             const float* __restrict__ sd,
                                             const float* __restrict__ vt,
                                             float* __restrict__ JS) {
    int row = blockIdx.x % 11;
    int c   = blockIdx.x / 11;       // 7 chunks of 1024 v
    int tid = threadIdx.x;
    int lane = tid & 63;
    const float* src = (row < NBETA) ? (sd + (size_t)row * VSTR) : vt;

    float acc[72];
#pragma unroll
    for (int o = 0; o < 72; o++) acc[o] = 0.f;

    for (int iv = 0; iv < 4; ++iv) {
        int v = c * 1024 + iv * 256 + tid;
        float jrg[24];
        float s0 = 0.f, s1 = 0.f, s2 = 0.f;
        if (v < NV) {
#pragma unroll
            for (int q = 0; q < 6; q++) {
                float4 f = *(const float4*)&Jreg[v * NJ + q * 4];
                jrg[q * 4 + 0] = f.x; jrg[q * 4 + 1] = f.y;
                jrg[q * 4 + 2] = f.z; jrg[q * 4 + 3] = f.w;
            }
            s0 = src[3 * v]; s1 = src[3 * v + 1]; s2 = src[3 * v + 2];
        } else {
#pragma unroll
            for (int q = 0; q < 24; q++) jrg[q] = 0.f;
        }
#pragma unroll
        for (int j = 0; j < 24; j++) {
            acc[j * 3 + 0] += jrg[j] * s0;
            acc[j * 3 + 1] += jrg[j] * s1;
            acc[j * 3 + 2] += jrg[j] * s2;
        }
    }
#pragma unroll
    for (int o = 0; o < 72; o++) {
#pragma unroll
        for (int off = 1; off < 64; off <<= 1)
            acc[o] += __shfl_xor(acc[o], off);
    }
    if (lane == 0) {
#pragma unroll
        for (int o = 0; o < 72; o++) atomicAdd(&JS[row * 72 + o], acc[o]);
    }
}

// per-batch: Rodrigues, pose_feature -> coefT, joint locations, kinematic chain -> A (rot+trans)
__global__ __launch_bounds__(64) void k_pose(const float* __restrict__ beta,
                                             const float* __restrict__ theta,
                                             const float* __restrict__ JS,
                                             float* __restrict__ coefT,
                                             float* __restrict__ Aw) {
    int n = blockIdx.x;
    int tid = threadIdx.x;
    __shared__ float Rs[24][9];
    __shared__ float Jl[24][3];
    __shared__ float G[24][12];

    if (tid < NJ) {
        int j = tid;
        float x = theta[n * 72 + j * 3 + 0];
        float y = theta[n * 72 + j * 3 + 1];
        float z = theta[n * 72 + j * 3 + 2];
        float ang = sqrtf(x * x + y * y + z * z + 1e-8f);
        float inv = 1.0f / ang;
        float rx = x * inv, ry = y * inv, rz = z * inv;
        float ct = cosf(ang), st = sinf(ang), oc = 1.0f - ct;
        float R[9];
        R[0] = ct + oc * rx * rx;  R[1] = -st * rz + oc * rx * ry; R[2] =  st * ry + oc * rx * rz;
        R[3] =  st * rz + oc * ry * rx; R[4] = ct + oc * ry * ry;  R[5] = -st * rx + oc * ry * rz;
        R[6] = -st * ry + oc * rz * rx; R[7] =  st * rx + oc * rz * ry; R[8] = ct + oc * rz * rz;
#pragma unroll
        for (int e = 0; e < 9; e++) Rs[j][e] = R[e];
        if (j >= 1) {
#pragma unroll
            for (int e = 0; e < 9; e++)
                coefT[(size_t)((j - 1) * 9 + e) * NB + n] =
                    R[e] - ((e == 0 || e == 4 || e == 8) ? 1.0f : 0.0f);
        }
    }
    if (tid < NBETA) coefT[(size_t)(NPOSE + tid) * NB + n] = beta[n * NBETA + tid];
    if (tid == 63)   coefT[(size_t)217 * NB + n] = 1.0f;
    __syncthreads();

    for (int idx = tid; idx < 72; idx += 64) {
        int j = idx / 3, a = idx - j * 3;
        float acc = JS[(NBETA * NJ + j) * 3 + a];
#pragma unroll
        for (int b = 0; b < NBETA; b++) acc += beta[n * NBETA + b] * JS[(b * NJ + j) * 3 + a];
        Jl[j][a] = acc;
    }
    __syncthreads();

    if (tid < 12) {
        int r = tid >> 2, cc = tid & 3;
        G[0][tid] = (cc < 3) ? Rs[0][r * 3 + cc] : Jl[0][r];
    }
    __syncthreads();

    const int PAR[24] = {0,0,0,0,1,2,3,4,5,6,7,8,9,9,9,12,13,14,16,17,18,19,20,21};
#pragma unroll
    for (int i = 1; i < NJ; i++) {
        int p = PAR[i];
        if (tid < 12) {
            int r = tid >> 2, cc = tid & 3;
            float g0 = G[p][r * 4 + 0], g1 = G[p][r * 4 + 1];
            float g2 = G[p][r * 4 + 2], g3 = G[p][r * 4 + 3];
            float val;
            if (cc < 3) {
                val = g0 * Rs[i][cc] + g1 * Rs[i][3 + cc] + g2 * Rs[i][6 + cc];
            } else {
                float t0 = Jl[i][0] - Jl[p][0];
                float t1 = Jl[i][1] - Jl[p][1];
                float t2 = Jl[i][2] - Jl[p][2];
                val = g0 * t0 + g1 * t1 + g2 * t2 + g3;
            }
            G[i][tid] = val;
        }
        __syncthreads();
    }

    for (int idx = tid; idx < 288; idx += 64) {
        int j = idx / 12, e = idx - j * 12;
        float val;
        if (e < 9) {
            int r = e / 3, cc = e - 3 * (e / 3);
            val = G[j][r * 4 + cc];
        } else {
            int r = e - 9;
            val = G[j][r * 4 + 3] -
                  (G[j][r * 4 + 0] * Jl[j][0] + G[j][r * 4 + 1] * Jl[j][1] +
                   G[j][r * 4 + 2] * Jl[j][2]);
        }
        Aw[(size_t)n * 288 + idx] = val;
    }
}

// MFMA bf16 hi/lo GEMM: OUT[r][a*456+col] += sum_v AT[a][r][v]*cw[col][v]
__global__ __launch_bounds__(256) void k_gemmP(const unsigned short* __restrict__ ATH,
                                               const unsigned short* __restrict__ ATL,
                                               const unsigned short* __restrict__ cwH,
                                               const unsigned short* __restrict__ cwL,
                                               float* __restrict__ OUTB) {
    int bid = blockIdx.x;
    int mt = bid & 3;
    int nt = (bid >> 2) & 7;
    int a  = (bid >> 5) % 3;
    int ks = bid / 96;
    int mb = mt * 64, nb = nt * 64;

    __shared__ __align__(16) short As[2][64][40];
    __shared__ __align__(16) short Bs[2][64][40];

    int tid = threadIdx.x;
    int row = tid >> 2, ch = tid & 3;
    int lane = tid & 63, wv = tid >> 6;
    int wm = wv >> 1, wn = wv & 1;
    int lr = lane & 15, lc = lane >> 4;

    bool okA = (mb + row) < AR;
    bool okB = (nb + row) < NKJ;
    const unsigned short* pAH = ATH + ((size_t)a * AR + (okA ? mb + row : 0)) * VP + ch * 8;
    const unsigned short* pAL = ATL + ((size_t)a * AR + (okA ? mb + row : 0)) * VP + ch * 8;
    const unsigned short* pBH = cwH + (size_t)(okB ? nb + row : 0) * VP + ch * 8;
    const unsigned short* pBL = cwL + (size_t)(okB ? nb + row : 0) * VP + ch * 8;

    f32x4 acc[2][2] = {};

    for (int s = 0; s < KCH / 32; ++s) {
        int vb = ks * KCH + s * 32;
        int4 z; z.x = z.y = z.z = z.w = 0;
        int4 vah = okA ? *(const int4*)(pAH + vb) : z;
        int4 valo = okA ? *(const int4*)(pAL + vb) : z;
        int4 vbh = okB ? *(const int4*)(pBH + vb) : z;
        int4 vblo = okB ? *(const int4*)(pBL + vb) : z;
        __syncthreads();
        *(int4*)&As[0][row][ch * 8] = vah;
        *(int4*)&As[1][row][ch * 8] = valo;
        *(int4*)&Bs[0][row][ch * 8] = vbh;
        *(int4*)&Bs[1][row][ch * 8] = vblo;
        __syncthreads();

        bf16x8 aH[2], aL[2], bH[2], bL[2];
#pragma unroll
        for (int t = 0; t < 2; ++t) {
            aH[t] = *(const bf16x8*)&As[0][wm * 32 + t * 16 + lr][lc * 8];
            aL[t] = *(const bf16x8*)&As[1][wm * 32 + t * 16 + lr][lc * 8];
            bH[t] = *(const bf16x8*)&Bs[0][wn * 32 + t * 16 + lr][lc * 8];
            bL[t] = *(const bf16x8*)&Bs[1][wn * 32 + t * 16 + lr][lc * 8];
        }
#pragma unroll
        for (int mi = 0; mi < 2; ++mi)
#pragma unroll
            for (int ni = 0; ni < 2; ++ni) {
                acc[mi][ni] = __builtin_amdgcn_mfma_f32_16x16x32_bf16(aH[mi], bH[ni], acc[mi][ni], 0, 0, 0);
                acc[mi][ni] = __builtin_amdgcn_mfma_f32_16x16x32_bf16(aH[mi], bL[ni], acc[mi][ni], 0, 0, 0);
                acc[mi][ni] = __builtin_amdgcn_mfma_f32_16x16x32_bf16(aL[mi], bH[ni], acc[mi][ni], 0, 0, 0);
            }
    }

#pragma unroll
    for (int mi = 0; mi < 2; ++mi)
#pragma unroll
        for (int ni = 0; ni < 2; ++ni)
#pragma unroll
            for (int q = 0; q < 4; ++q) {
                int r = mb + wm * 32 + mi * 16 + lc * 4 + q;
                int c = nb + wn * 32 + ni * 16 + lr;
                if (r < AR && c < NKJ)
                    atomicAdd(&OUTB[(size_t)r * NCOL + a * NKJ + c], acc[mi][ni][q]);
            }
}

// M[n][col] = sum_r coefT[r][n] * OUT[r][col]   (1024 x 1368 x 218), 32x64 tiles (704 blocks)
__global__ __launch_bounds__(256) void k_gemmM(const float* __restrict__ coefT,
                                               const float* __restrict__ OUTB,
                                               float* __restrict__ M) {
    int bid = blockIdx.x;
    int mt = bid & 31, nt = bid >> 5;   // 32 x 22
    int mb = mt * 32, nb = nt * 64;
    __shared__ float Cs[32][32];
    __shared__ float Bs[32][64];
    int tid = threadIdx.x;
    int tm = tid & 15, tn = tid >> 4;
    float acc[2][4] = {};
    for (int kb = 0; kb < KR; kb += 32) {
#pragma unroll
        for (int p = 0; p < 4; p++) {
            int idx = tid + p * 256;
            int kk = idx >> 5, nl = idx & 31;
            int r = kb + kk;
            Cs[kk][nl] = (r < KR) ? coefT[(size_t)r * NB + mb + nl] : 0.f;
        }
#pragma unroll
        for (int p = 0; p < 8; p++) {
            int idx = tid + p * 256;
            int kk = idx >> 6, m = idx & 63;
            int r = kb + kk;
            int col = nb + m;
            Bs[kk][m] = (r < KR && col < NCOL) ? OUTB[(size_t)r * NCOL + col] : 0.f;
        }
        __syncthreads();
#pragma unroll
        for (int kk = 0; kk < 32; kk++) {
            float2 cv = *(const float2*)&Cs[kk][tm * 2];
            float4 bv = *(const float4*)&Bs[kk][tn * 4];
            float cm[2] = {cv.x, cv.y};
            float bn[4] = {bv.x, bv.y, bv.z, bv.w};
#pragma unroll
            for (int i = 0; i < 2; i++)
#pragma unroll
                for (int j = 0; j < 4; j++) acc[i][j] += cm[i] * bn[j];
        }
        __syncthreads();
    }
#pragma unroll
    for (int i = 0; i < 2; i++) {
        int n = mb + tm * 2 + i;
#pragma unroll
        for (int j = 0; j < 4; j++) {
            int col = nb + tn * 4 + j;
            if (col < NCOL) M[(size_t)n * NCOL + col] = acc[i][j];
        }
    }
}

// joints[n,k,a] = sum_j R_A[n,j,a,:].m[n,k,j,:] + s[k,j]*t_A[n,j,a]
__global__ void k_joints(const float* __restrict__ M, const float* __restrict__ Aw,
                         const float* __restrict__ OUTB, float* __restrict__ out) {
    int idx = blockIdx.x * 256 + threadIdx.x;
    if (idx >= NB * NK) return;
    int n = idx / NK, k = idx - n * NK;
    const float* A = Aw + (size_t)n * 288;
    const float* Mn = M + (size_t)n * NCOL;
    float o0 = 0.f, o1 = 0.f, o2 = 0.f;
#pragma unroll
    for (int j = 0; j < NJ; j++) {
        int kj = k * NJ + j;
        float m0 = Mn[kj];
        float m1 = Mn[NKJ + kj];
        float m2 = Mn[2 * NKJ + kj];
        float s = OUTB[(size_t)218 * NCOL + kj];
        const float* Aj = A + j * 12;
        o0 += Aj[0] * m0 + Aj[1] * m1 + Aj[2] * m2 + s * Aj[9];
        o1 += Aj[3] * m0 + Aj[4] * m1 + Aj[5] * m2 + s * Aj[10];
        o2 += Aj[6] * m0 + Aj[7] * m1 + Aj[8] * m2 + s * Aj[11];
    }
    out[idx * 3 + 0] = o0;
    out[idx * 3 + 1] = o1;
    out[idx * 3 + 2] = o2;
}

extern "C" void kernel_launch(void* const* d_in, const int* in_sizes, int n_in,
                              void* d_out, int out_size, void* d_ws, size_t ws_size,
                              hipStream_t stream) {
    const float* beta  = (const float*)d_in[0];
    const float* theta = (const float*)d_in[1];
    const float* vt    = (const float*)d_in[2];
    const float* sd    = (const float*)d_in[3];
    const float* Jreg  = (const float*)d_in[4];
    const float* pd    = (const float*)d_in[5];
    const float* w     = (const float*)d_in[6];
    const float* jr    = (const float*)d_in[7];

    unsigned short* ush = (unsigned short*)d_ws;
    unsigned short* ATH = ush;
    unsigned short* ATL = ATH + N_AT;
    unsigned short* cwH = ATL + N_AT;
    unsigned short* cwL = cwH + N_CW;
    float* fbase = (float*)(ush + USH_TOTAL);
    float* OUTB  = fbase;
    float* coefT = OUTB + SZ_OUT;
    float* Aw    = coefT + SZ_COEF;
    float* JS    = Aw + SZ_AW;
    float* M     = JS + SZ_JS;
    float* out   = (float*)d_out;

    // zero OUTB..JS (contiguous) in one memset: OUTB + coefT + Aw + JS
    hipMemsetAsync(OUTB, 0, (SZ_OUT + SZ_COEF + SZ_AW + SZ_JS) * sizeof(float), stream);
    k_at2<<<(3 * AR * VP4 + 255) / 256, 256, 0, stream>>>(pd, sd, vt, ATH, ATL);
    k_cw2<<<(NKJ * VP4 + 255) / 256, 256, 0, stream>>>(jr, w, cwH, cwL);
    k_js2<<<11 * 7, 256, 0, stream>>>(Jreg, sd, vt, JS);
    k_pose<<<NB, 64, 0, stream>>>(beta, theta, JS, coefT, Aw);
    k_gemmP<<<4 * 8 * 3 * KSPLIT, 256, 0, stream>>>(ATH, ATL, cwH, cwL, OUTB);
    k_gemmM<<<32 * 22, 256, 0, stream>>>(coefT, OUTB, M);
    k_joints<<<(NB * NK + 255) / 256, 256, 0, stream>>>(M, Aw, OUTB, out);
}